// Round 6
// baseline (620.368 us; speedup 1.0000x reference)
//
#include <hip/hip_runtime.h>
#include <cstdint>
#include <cstddef>

#define B_ 128
#define E_ 1024
#define R_ 64
#define T_ 4
#define IN_ 2112
#define G_ 256   // 4*R

typedef __attribute__((ext_vector_type(4))) float f32x4;
typedef __attribute__((ext_vector_type(8))) __bf16 bf16x8;

__device__ __forceinline__ unsigned short f2bf(float f) {
  unsigned int u = __float_as_uint(f);
  u += 0x7fffu + ((u >> 16) & 1u);   // RNE
  return (unsigned short)(u >> 16);
}
__device__ __forceinline__ unsigned int pack2(float lo, float hi) {
  return (unsigned int)f2bf(lo) | ((unsigned int)f2bf(hi) << 16);
}
__device__ __forceinline__ float wred_sum(float v) {
#pragma unroll
  for (int m = 32; m > 0; m >>= 1) v += __shfl_xor(v, m, 64);
  return v;
}
__device__ __forceinline__ float wred_max(float v) {
#pragma unroll
  for (int m = 32; m > 0; m >>= 1) v = fmaxf(v, __shfl_xor(v, m, 64));
  return v;
}
__device__ __forceinline__ float fast_sig(float x) {
  return __builtin_amdgcn_rcpf(1.f + __expf(-x));
}
__device__ __forceinline__ float fast_tanh(float x) {
  return 1.f - 2.f * __builtin_amdgcn_rcpf(1.f + __expf(2.f * x));
}

__device__ __forceinline__ void gload_lds16(const void* g, void* l) {
  __builtin_amdgcn_global_load_lds(
      (const __attribute__((address_space(1))) unsigned int*)g,
      (__attribute__((address_space(3))) unsigned int*)l, 16, 0, 0);
}

// ============ fused0: blocks [0,128) = LSTM recurrence + softmax head;
//              blocks [128,640) = round-0 GEMM reading kb in FP32 with a
//              double-buffered reg->LDS pipeline (1 barrier/K-step), converting
//              in-register, side-writing kbbf (bf16) exactly once per element.
__global__ __launch_bounds__(256) void fused0_kernel(
    const float* __restrict__ x, const float* __restrict__ kb,
    const float* __restrict__ Wih0, const float* __restrict__ Whh0,
    const float* __restrict__ bih0, const float* __restrict__ bhh0,
    const float* __restrict__ Wih, const float* __restrict__ Whh,
    const float* __restrict__ bih, const float* __restrict__ bhh,
    unsigned short* __restrict__ kb_bf,
    float* __restrict__ part,
    float* __restrict__ h2_out, float* __restrict__ att_out) {
  __shared__ __align__(16) unsigned char smem[40960];
  const int tid = threadIdx.x;
  const int bid = blockIdx.x;

  if (bid >= 128) {
    // ---------------- round-0 GEMM: part[r][b][e] = sum_f A[b,f]*kb[r,e,f]
    //  A[b,f] = f2bf(x[b, 64+f])  (att[0,b,0]==1.0 exactly)
    //  fp32 loads double-buffered in regs; convert->LDS after MFMA (T14 split).
    unsigned short* As = (unsigned short*)smem;          // [2][128*40]
    unsigned short* Bs = As + 2 * 5120;                  // [2][128*40]
    const int g = bid - 128;
    const int et = g & 7, r = g >> 3;
    const int row = tid >> 1;
    const int c0 = (tid & 1) * 16;
    const float* aptr = x + (size_t)row * IN_ + R_ + c0;
    const float* bptr = kb + (size_t)r * 1048576 + (size_t)(et * 128 + row) * 1024 + c0;
    unsigned short* kdst = kb_bf + (size_t)r * 1048576 + (size_t)(et * 128 + row) * 1024 + c0;
    const int wv = tid >> 6, lane = tid & 63;
    const int wm = (wv & 1) * 64, wn = (wv >> 1) * 64;
    const int fr = lane & 15, koff = (lane >> 4) * 8;

    float4 ra0, ra1, ra2, ra3, rb0, rb1, rb2, rb3;
    auto loadregs = [&](int kk) {
      ra0 = *(const float4*)(aptr + kk * 32);
      ra1 = *(const float4*)(aptr + kk * 32 + 4);
      ra2 = *(const float4*)(aptr + kk * 32 + 8);
      ra3 = *(const float4*)(aptr + kk * 32 + 12);
      rb0 = *(const float4*)(bptr + kk * 32);
      rb1 = *(const float4*)(bptr + kk * 32 + 4);
      rb2 = *(const float4*)(bptr + kk * 32 + 8);
      rb3 = *(const float4*)(bptr + kk * 32 + 12);
    };
    auto cvtwrite = [&](int buf, int kk) {
      unsigned short* adst = As + buf * 5120 + row * 40 + c0;
      unsigned short* bdst = Bs + buf * 5120 + row * 40 + c0;
      uint4 u;
      u.x = pack2(ra0.x, ra0.y); u.y = pack2(ra0.z, ra0.w);
      u.z = pack2(ra1.x, ra1.y); u.w = pack2(ra1.z, ra1.w);
      *(uint4*)adst = u;
      u.x = pack2(ra2.x, ra2.y); u.y = pack2(ra2.z, ra2.w);
      u.z = pack2(ra3.x, ra3.y); u.w = pack2(ra3.z, ra3.w);
      *(uint4*)(adst + 8) = u;
      uint4 ub;
      ub.x = pack2(rb0.x, rb0.y); ub.y = pack2(rb0.z, rb0.w);
      ub.z = pack2(rb1.x, rb1.y); ub.w = pack2(rb1.z, rb1.w);
      *(uint4*)bdst = ub;
      *(uint4*)(kdst + kk * 32) = ub;        // side-write bf16 kb
      ub.x = pack2(rb2.x, rb2.y); ub.y = pack2(rb2.z, rb2.w);
      ub.z = pack2(rb3.x, rb3.y); ub.w = pack2(rb3.z, rb3.w);
      *(uint4*)(bdst + 8) = ub;
      *(uint4*)(kdst + kk * 32 + 8) = ub;
    };

    f32x4 acc[4][4];
#pragma unroll
    for (int mt = 0; mt < 4; mt++)
#pragma unroll
      for (int nt = 0; nt < 4; nt++)
#pragma unroll
        for (int q = 0; q < 4; q++) acc[mt][nt][q] = 0.f;

    loadregs(0);
    cvtwrite(0, 0);
    __syncthreads();
    int cur = 0;
    for (int kk = 0; kk < 32; kk++) {
      if (kk < 31) loadregs(kk + 1);   // issue next-tile fp32 loads early
      bf16x8 af[4], bfr[4];
#pragma unroll
      for (int mt = 0; mt < 4; mt++)
        af[mt] = *(const bf16x8*)(As + cur * 5120 + (wm + mt * 16 + fr) * 40 + koff);
#pragma unroll
      for (int nt = 0; nt < 4; nt++)
        bfr[nt] = *(const bf16x8*)(Bs + cur * 5120 + (wn + nt * 16 + fr) * 40 + koff);
#pragma unroll
      for (int mt = 0; mt < 4; mt++)
#pragma unroll
        for (int nt = 0; nt < 4; nt++)
          acc[mt][nt] = __builtin_amdgcn_mfma_f32_16x16x32_bf16(af[mt], bfr[nt], acc[mt][nt], 0, 0, 0);
      if (kk < 31) cvtwrite(cur ^ 1, kk + 1);   // convert+write AFTER MFMA (loads landed)
      __syncthreads();
      cur ^= 1;
    }
    const int crow = (lane >> 4) * 4;
    float* pout = part + (size_t)r * 131072;
#pragma unroll
    for (int mt = 0; mt < 4; mt++)
#pragma unroll
      for (int nt = 0; nt < 4; nt++)
#pragma unroll
        for (int q = 0; q < 4; q++)
          pout[(wm + mt * 16 + crow + q) * 1024 + et * 128 + wn + nt * 16 + fr] = acc[mt][nt][q];
    return;
  }

  // ---------------- LSTM branch (b = bid) ----------------
  float* xrow    = (float*)smem;            // 2112
  float* pre_lds = xrow + IN_;              // 256
  float* hbuf    = pre_lds + G_;            // 64
  float* zbuf    = hbuf + R_;               // 2*256
  float* hs_out  = zbuf + 2 * G_;           // 4*64
  float* hmat    = hs_out + T_ * R_;        // 4*64

  const int b = bid;
  const int lane = tid & 63, wv = tid >> 6;
  const int s = tid & 63;

  for (int l = tid; l < IN_; l += 256) xrow[l] = x[b * IN_ + l];
  __syncthreads();

  // pre0, coalesced: wave wv computes outputs g in [wv*64, wv*64+64)
  {
    const int gbase = wv * 64;
#pragma unroll 2
    for (int gg = 0; gg < 64; gg++) {
      const float* wr = Wih0 + (size_t)(gbase + gg) * IN_;
      float4 s4 = {0.f, 0.f, 0.f, 0.f};
#pragma unroll
      for (int k = 0; k < 8; k++) {
        float4 w = *(const float4*)(wr + (lane + 64 * k) * 4);
        float4 xv = *(const float4*)(&xrow[(lane + 64 * k) * 4]);
        s4.x += w.x * xv.x; s4.y += w.y * xv.y;
        s4.z += w.z * xv.z; s4.w += w.w * xv.w;
      }
      float part_ = (s4.x + s4.y) + (s4.z + s4.w);
      part_ += wr[2048 + lane] * xrow[2048 + lane];
      float tot = wred_sum(part_);
      if (lane == 0) pre_lds[gbase + gg] = tot;
    }
  }
  float p0 = pre_lds[tid] + bih0[tid] + bhh0[tid];

  float4 w4[16];
  float pret[T_];

  auto scan = [&]() {
    __syncthreads();
    hbuf[s] = 0.f;
    float creg = 0.f;
#pragma unroll
    for (int t = 0; t < T_; t++) {
      float z0 = pret[t], z1 = 0.f, z2 = 0.f, z3 = 0.f;
#pragma unroll
      for (int q = 0; q < 16; q += 4) {
        float4 h0 = *(const float4*)(&hbuf[q * 4]);
        float4 h1 = *(const float4*)(&hbuf[q * 4 + 4]);
        float4 h2v = *(const float4*)(&hbuf[q * 4 + 8]);
        float4 h3 = *(const float4*)(&hbuf[q * 4 + 12]);
        z0 += h0.x * w4[q].x + h0.y * w4[q].y + h0.z * w4[q].z + h0.w * w4[q].w;
        z1 += h1.x * w4[q + 1].x + h1.y * w4[q + 1].y + h1.z * w4[q + 1].z + h1.w * w4[q + 1].w;
        z2 += h2v.x * w4[q + 2].x + h2v.y * w4[q + 2].y + h2v.z * w4[q + 2].z + h2v.w * w4[q + 2].w;
        z3 += h3.x * w4[q + 3].x + h3.y * w4[q + 3].y + h3.z * w4[q + 3].z + h3.w * w4[q + 3].w;
      }
      zbuf[(t & 1) * G_ + tid] = (z0 + z1) + (z2 + z3);
      __syncthreads();
      float iv = fast_sig(zbuf[(t & 1) * G_ + s]);
      float fv = fast_sig(zbuf[(t & 1) * G_ + R_ + s]);
      float gv = fast_tanh(zbuf[(t & 1) * G_ + 2 * R_ + s]);
      float ov = fast_sig(zbuf[(t & 1) * G_ + 3 * R_ + s]);
      creg = fv * creg + iv * gv;
      float h = ov * fast_tanh(creg);
      hbuf[s] = h;
      hs_out[t * R_ + s] = h;
    }
  };

  // layer 0
#pragma unroll
  for (int t = 0; t < T_; t++) pret[t] = p0;
#pragma unroll
  for (int q = 0; q < 16; q++)
    w4[q] = *(const float4*)(Whh0 + (size_t)tid * R_ + q * 4);
  scan();

  // layers 1..3
  for (int l = 0; l < T_ - 1; l++) {
#pragma unroll
    for (int q = 0; q < 16; q++)
      w4[q] = *(const float4*)(Wih + ((size_t)l * G_ + tid) * R_ + q * 4);
    const float bsum = bih[l * G_ + tid] + bhh[l * G_ + tid];
#pragma unroll
    for (int t = 0; t < T_; t++) {
      float p = bsum;
#pragma unroll
      for (int q = 0; q < 16; q++) {
        float4 hv = *(const float4*)(&hs_out[t * R_ + q * 4]);
        p += hv.x * w4[q].x + hv.y * w4[q].y + hv.z * w4[q].z + hv.w * w4[q].w;
      }
      pret[t] = p;
    }
#pragma unroll
    for (int q = 0; q < 16; q++)
      w4[q] = *(const float4*)(Whh + ((size_t)l * G_ + tid) * R_ + q * 4);
    scan();
  }

  // softmax head: wave wv handles timestep t = wv
  {
    float v = hs_out[wv * R_ + lane];
    float mx = wred_max(v);
    float ev = expf(v - mx);
    float sm = wred_sum(ev);
    float hval = ev / sm;                 // h = softmax(hs)
    hmat[wv * R_ + lane] = hval;
    float mx2 = wred_max(hval);
    float e2 = expf(hval - mx2);
    float s2 = wred_sum(e2);
    h2_out[(wv * B_ + b) * R_ + lane] = e2 / s2;   // h2 = softmax(h)
    __syncthreads();
    float dots[T_];
    for (int k = 0; k <= wv; k++)
      dots[k] = wred_sum(hmat[k * R_ + lane] * hmat[wv * R_ + lane]);
    if (lane == 0) {
      float mx3 = dots[0];
      for (int k = 1; k <= wv; k++) mx3 = fmaxf(mx3, dots[k]);
      float ss = 0.f, es[T_];
      for (int k = 0; k <= wv; k++) { es[k] = expf(dots[k] - mx3); ss += es[k]; }
      for (int k = 0; k <= wv; k++) att_out[(wv * B_ + b) * 4 + k] = es[k] / ss;
    }
  }
}

// ============ GEMM rounds 1-3: part[r][b][e] = sum_f prev[b,f]*kb[r,e,f] =======
// grid (16 e-tiles, 64 r) = 1024 blocks, tile 128x64 -> ~4 blocks/CU so block
// pipelines cover each other's barrier drains. 2-phase global_load_lds staging,
// single barrier per K-step. Per-output K-order identical -> bitwise-same part.
__global__ __launch_bounds__(256) void gemm_bf_kernel(
    const unsigned short* __restrict__ Abf,   // [128][1024] bf16
    const unsigned short* __restrict__ Kbf,   // [64][1024][1024] bf16
    float* __restrict__ part) {               // [64][128][1024]
  __shared__ unsigned short As[2][128 * 32];  // 8 KB per buf
  __shared__ unsigned short Bs[2][64 * 32];   // 4 KB per buf
  const int tid = threadIdx.x, wv = tid >> 6, lane = tid & 63;
  const int et = blockIdx.x, r = blockIdx.y;  // et in [0,16)
  const int wm = (wv & 1) * 64, wn = (wv >> 1) * 32;
  const int fr = lane & 15, koff = (lane >> 4) * 8;

  // staging: A rows [wv*32,wv*32+32) (2 instr), B rows [wv*16,wv*16+16) (1 instr)
  const int srowA = wv * 32 + (lane >> 2);
  const int srowB = wv * 16 + (lane >> 2);
  const int scol = (lane & 3) * 8;
  const unsigned short* agp = Abf + (size_t)srowA * 1024 + scol;
  const unsigned short* bgp = Kbf + (size_t)r * 1048576 + (size_t)(et * 64 + srowB) * 1024 + scol;

  f32x4 acc[4][2];
#pragma unroll
  for (int mt = 0; mt < 4; mt++)
#pragma unroll
    for (int nt = 0; nt < 2; nt++)
#pragma unroll
      for (int q = 0; q < 4; q++) acc[mt][nt][q] = 0.f;

  auto stage = [&](int buf, int kk) {
    gload_lds16(agp + kk * 32,             As[buf] + wv * 1024);
    gload_lds16(agp + kk * 32 + 16 * 1024, As[buf] + wv * 1024 + 512);
    gload_lds16(bgp + kk * 32,             Bs[buf] + wv * 512);
  };

  stage(0, 0);
  __syncthreads();   // tile 0 resident
  int cur = 0;
  for (int kk = 0; kk < 32; kk++) {
    if (kk < 31) stage(cur ^ 1, kk + 1);   // issue next-tile loads early
    bf16x8 af[4], bfr[2];
#pragma unroll
    for (int mt = 0; mt < 4; mt++)
      af[mt] = *(const bf16x8*)(As[cur] + (wm + mt * 16 + fr) * 32 + koff);
#pragma unroll
    for (int nt = 0; nt < 2; nt++)
      bfr[nt] = *(const bf16x8*)(Bs[cur] + (wn + nt * 16 + fr) * 32 + koff);
#pragma unroll
    for (int mt = 0; mt < 4; mt++)
#pragma unroll
      for (int nt = 0; nt < 2; nt++)
        acc[mt][nt] = __builtin_amdgcn_mfma_f32_16x16x32_bf16(af[mt], bfr[nt], acc[mt][nt], 0, 0, 0);
    __syncthreads();   // drains prefetch (vmcnt) + frag reads (lgkm); flip
    cur ^= 1;
  }
  const int crow = (lane >> 4) * 4;
  float* pout = part + (size_t)r * 131072;
#pragma unroll
  for (int mt = 0; mt < 4; mt++)
#pragma unroll
    for (int nt = 0; nt < 2; nt++)
#pragma unroll
      for (int q = 0; q < 4; q++)
        pout[(wm + mt * 16 + crow + q) * 1024 + et * 64 + wn + nt * 16 + fr] = acc[mt][nt][q];
}

// ============ mid: mem_it = sum_r h2[it,b,r]*part[r,b,e]; prep next prev ========
__global__ __launch_bounds__(256) void mid_kernel(
    const float* __restrict__ part, const float* __restrict__ h2,
    const float* __restrict__ att, const float* __restrict__ x,
    float* __restrict__ mem, unsigned short* __restrict__ prev_bf, int it) {
  const int idx = blockIdx.x * 256 + threadIdx.x;   // 131072
  const int b = idx >> 10, e = idx & 1023;
  const float* h2row = h2 + (it * B_ + b) * R_;     // b uniform per block
  const float* pp = part + idx;
  float s = 0.f;
#pragma unroll 8
  for (int rr = 0; rr < 64; rr++) s += h2row[rr] * pp[(size_t)rr * 131072];
  mem[it * 131072 + idx] = s;
  if (it < 3) {
    const float* arow = att + ((it + 1) * B_ + b) * 4;
    float acc = arow[0] * x[b * IN_ + R_ + e];
    for (int k = 1; k <= it; k++) acc += arow[k] * mem[(k - 1) * 131072 + idx];
    acc += arow[it + 1] * s;
    prev_bf[idx] = f2bf(acc);
  }
}

// ============ fallback path (small ws): round-0 fp32-kb gemm ====================
__global__ __launch_bounds__(256) void prep_fp32_kernel(
    const float* __restrict__ x, const float* __restrict__ att,
    const float* __restrict__ mem, float* __restrict__ prev,
    float* __restrict__ newmem, int it) {
  const int idx = blockIdx.x * 256 + threadIdx.x;
  const int b = idx >> 10, e = idx & 1023;
  const float* arow = att + (it * B_ + b) * 4;
  float acc = arow[0] * x[b * IN_ + R_ + e];
  for (int k = 1; k <= it; k++)
    acc += arow[k] * mem[(k - 1) * (B_ * E_) + b * E_ + e];
  prev[idx] = acc;
  newmem[idx] = 0.f;
}

__global__ __launch_bounds__(256) void gemm_fp32_kernel(
    const float* __restrict__ prev, const float* __restrict__ h2,
    const float* __restrict__ kb, float* __restrict__ out) {
  __shared__ unsigned short As[128 * 40];
  __shared__ unsigned short Bs[128 * 40];
  __shared__ float h2s[128];
  const int tid = threadIdx.x;
  const int et = blockIdx.x;
  const int r = blockIdx.y;
  if (tid < 128) h2s[tid] = h2[tid * 64 + r];
  __syncthreads();
  const int row = tid >> 1;
  const int c0 = (tid & 1) * 16;
  const float hsc = h2s[row];
  const float* aptr = prev + row * 1024 + c0;
  const float* bptr = kb + (size_t)r * (1024u * 1024u) + (size_t)(et * 128 + row) * 1024 + c0;
  unsigned short* adst = As + row * 40 + c0;
  unsigned short* bdst = Bs + row * 40 + c0;
  const int wv = tid >> 6, lane = tid & 63;
  const int wm = (wv & 1) * 64, wn = (wv >> 1) * 64;
  const int fr = lane & 15, koff = (lane >> 4) * 8;
  f32x4 acc[4][4];
#pragma unroll
  for (int mt = 0; mt < 4; mt++)
#pragma unroll
    for (int nt = 0; nt < 4; nt++)
#pragma unroll
      for (int q = 0; q < 4; q++) acc[mt][nt][q] = 0.f;
  for (int kk = 0; kk < 32; kk++) {
    const float4 a0 = *(const float4*)(aptr + kk * 32);
    const float4 a1 = *(const float4*)(aptr + kk * 32 + 4);
    const float4 a2 = *(const float4*)(aptr + kk * 32 + 8);
    const float4 a3 = *(const float4*)(aptr + kk * 32 + 12);
    const float4 b0 = *(const float4*)(bptr + kk * 32);
    const float4 b1 = *(const float4*)(bptr + kk * 32 + 4);
    const float4 b2 = *(const float4*)(bptr + kk * 32 + 8);
    const float4 b3 = *(const float4*)(bptr + kk * 32 + 12);
    __syncthreads();
    uint4 u;
    u.x = pack2(a0.x * hsc, a0.y * hsc); u.y = pack2(a0.z * hsc, a0.w * hsc);
    u.z = pack2(a1.x * hsc, a1.y * hsc); u.w = pack2(a1.z * hsc, a1.w * hsc);
    *(uint4*)adst = u;
    u.x = pack2(a2.x * hsc, a2.y * hsc); u.y = pack2(a2.z * hsc, a2.w * hsc);
    u.z = pack2(a3.x * hsc, a3.y * hsc); u.w = pack2(a3.z * hsc, a3.w * hsc);
    *(uint4*)(adst + 8) = u;
    u.x = pack2(b0.x, b0.y); u.y = pack2(b0.z, b0.w);
    u.z = pack2(b1.x, b1.y); u.w = pack2(b1.z, b1.w);
    *(uint4*)bdst = u;
    u.x = pack2(b2.x, b2.y); u.y = pack2(b2.z, b2.w);
    u.z = pack2(b3.x, b3.y); u.w = pack2(b3.z, b3.w);
    *(uint4*)(bdst + 8) = u;
    __syncthreads();
    bf16x8 af[4], bfr[4];
#pragma unroll
    for (int mt = 0; mt < 4; mt++)
      af[mt] = *(const bf16x8*)(As + (wm + mt * 16 + fr) * 40 + koff);
#pragma unroll
    for (int nt = 0; nt < 4; nt++)
      bfr[nt] = *(const bf16x8*)(Bs + (wn + nt * 16 + fr) * 40 + koff);
#pragma unroll
    for (int mt = 0; mt < 4; mt++)
#pragma unroll
      for (int nt = 0; nt < 4; nt++)
        acc[mt][nt] = __builtin_amdgcn_mfma_f32_16x16x32_bf16(af[mt], bfr[nt], acc[mt][nt], 0, 0, 0);
  }
  const int crow = (lane >> 4) * 4;
  const int ccol = et * 128 + fr;
#pragma unroll
  for (int mt = 0; mt < 4; mt++)
#pragma unroll
    for (int nt = 0; nt < 4; nt++)
#pragma unroll
      for (int q = 0; q < 4; q++)
        atomicAdd(&out[(wm + mt * 16 + crow + q) * 1024 + ccol + wn + nt * 16], acc[mt][nt][q]);
}

// ============ score = sigmoid(-dot(mem4, tail)) =================================
__global__ __launch_bounds__(256) void score_kernel(
    const float* __restrict__ x, const float* __restrict__ mem4,
    float* __restrict__ out) {
  __shared__ float red[4];
  const int b = blockIdx.x, tid = threadIdx.x;
  float s = 0.f;
  for (int e = tid; e < E_; e += 256)
    s += mem4[b * E_ + e] * x[b * IN_ + R_ + E_ + e];
  s = wred_sum(s);
  if ((tid & 63) == 0) red[tid >> 6] = s;
  __syncthreads();
  if (tid == 0) {
    float t = red[0] + red[1] + red[2] + red[3];
    out[b] = 1.f / (1.f + expf(t));   // sigmoid(-t)
  }
}

extern "C" void kernel_launch(void* const* d_in, const int* in_sizes, int n_in,
                              void* d_out, int out_size, void* d_ws, size_t ws_size,
                              hipStream_t stream) {
  const float* x    = (const float*)d_in[0];
  const float* kb   = (const float*)d_in[1];
  const float* Wih0 = (const float*)d_in[2];
  const float* Whh0 = (const float*)d_in[3];
  const float* bih0 = (const float*)d_in[4];
  const float* bhh0 = (const float*)d_in[5];
  const float* Wih  = (const float*)d_in[6];
  const float* Whh  = (const float*)d_in[7];
  const float* bih  = (const float*)d_in[8];
  const float* bhh  = (const float*)d_in[9];

  float* ws    = (float*)d_ws;
  float* h2    = ws;                    // 32768
  float* att   = ws + 32768;            // 2048
  float* mem   = ws + 34816;            // 4*131072
  float* prevb = ws + 559104;           // 131072 (bf16 or fp32 prev)
  float* part  = ws + 690176;           // 64*131072 = 8388608
  float* kbbf  = ws + 9078784;          // 33554432 (64Mi bf16)
  const size_t need_big = (size_t)(9078784 + 33554432) * sizeof(float);  // ~170.5 MB
  const bool big = ws_size >= need_big;

  if (big) {
    // fused0: LSTM (128 blocks) + round-0 fp32-kb GEMM w/ kbbf production (512)
    fused0_kernel<<<640, 256, 0, stream>>>(x, kb, Wih0, Whh0, bih0, bhh0,
                                           Wih, Whh, bih, bhh,
                                           (unsigned short*)kbbf, part, h2, att);
    mid_kernel<<<512, 256, 0, stream>>>(part, h2, att, x, mem,
                                        (unsigned short*)prevb, 0);
    for (int i = 1; i < 4; i++) {
      gemm_bf_kernel<<<dim3(16, 64), 256, 0, stream>>>(
          (const unsigned short*)prevb, (const unsigned short*)kbbf, part);
      mid_kernel<<<512, 256, 0, stream>>>(part, h2, att, x, mem,
                                          (unsigned short*)prevb, i);
    }
  } else {
    // small-ws: LSTM via fused0's lstm branch only (grid=128 -> no gemm blocks)
    fused0_kernel<<<128, 256, 0, stream>>>(x, kb, Wih0, Whh0, bih0, bhh0,
                                           Wih, Whh, bih, bhh,
                                           (unsigned short*)prevb, mem, h2, att);
    for (int i = 0; i < 4; i++) {
      float* newmem = mem + i * (B_ * E_);
      prep_fp32_kernel<<<512, 256, 0, stream>>>(x, att, mem, prevb, newmem, i);
      gemm_fp32_kernel<<<dim3(8, 64), 256, 0, stream>>>(prevb, h2 + i * (B_ * R_), kb, newmem);
    }
  }
  score_kernel<<<128, 256, 0, stream>>>(x, mem + 3 * (B_ * E_), (float*)d_out);
}